// Round 7
// baseline (127.776 us; speedup 1.0000x reference)
//
#include <hip/hip_runtime.h>
#include <math.h>

// ln(2*pi) in f32 (reference uses jnp.log(2*PI) with truncated f32 PI)
#define LOG_2PI 1.8378770664093453f

__device__ __forceinline__ float elu_f(float x) {
    return x > 0.0f ? x : expm1f(x);
}
__device__ __forceinline__ float sigmoid_f(float x) {
    return 1.0f / (1.0f + expf(-x));
}

// ---------------------------------------------------------------------------
// K1: decoder. grid = 512 blocks = 128 k-tiles (2 latent rows) x 4 j-quarters
// (2 blocks/CU, 2 waves/SIMD -> latency-hidden vs the 1-block/CU version).
// Layers 1-3 computed redundantly per j-quarter (cheap); layer 4 does 196
// outputs per block, one per thread (2 k-dots each). Stores P^T (784 x 256)
// so K2's loads are lane-coalesced. Block 0 also zeroes K2's done-counter
// (kernel-boundary flush makes it visible to K2).
// ---------------------------------------------------------------------------
__global__ __launch_bounds__(256) void decoder_kernel(
    const float* __restrict__ z,
    const float* __restrict__ W1, const float* __restrict__ b1,
    const float* __restrict__ W2, const float* __restrict__ b2,
    const float* __restrict__ W3, const float* __restrict__ b3,
    const float* __restrict__ W4, const float* __restrict__ b4,
    float* __restrict__ PT, unsigned int* __restrict__ counter)
{
    __shared__ __align__(16) float h1[2][64];
    __shared__ __align__(16) float h2[2][128];
    __shared__ __align__(16) float h3[2][256];

    const int t  = threadIdx.x;
    const int kt = blockIdx.x >> 2;   // 0..127
    const int jq = blockIdx.x & 3;    // 0..3
    const int k0 = kt * 2;

    if (blockIdx.x == 0 && t == 0) counter[0] = 0u;

    // ---- layer 1: (2 k) x 64 outputs, dot over 2 ----
    if (t < 128) {
        int kl = t >> 6, o = t & 63;
        float z0 = z[(k0 + kl) * 2 + 0];
        float z1 = z[(k0 + kl) * 2 + 1];
        float v = fmaf(z0, W1[o * 2 + 0], fmaf(z1, W1[o * 2 + 1], b1[o]));
        h1[kl][o] = elu_f(v);
    }
    __syncthreads();

    // ---- layer 2: (2 k) x 128 outputs, dot over 64 ----
    {
        int kl = t >> 7, o = t & 127;
        const float4* wr = reinterpret_cast<const float4*>(W2 + o * 64);
        const float4* hr = reinterpret_cast<const float4*>(h1[kl]);
        float acc = b2[o];
        #pragma unroll
        for (int i = 0; i < 16; ++i) {
            float4 w = wr[i]; float4 a = hr[i];
            acc = fmaf(w.x, a.x, acc); acc = fmaf(w.y, a.y, acc);
            acc = fmaf(w.z, a.z, acc); acc = fmaf(w.w, a.w, acc);
        }
        h2[kl][o] = elu_f(acc);
    }
    __syncthreads();

    // ---- layer 3: (2 k) x 256 outputs, dot over 128 ----
    for (int idx = t; idx < 512; idx += 256) {
        int kl = idx >> 8, o = idx & 255;
        const float4* wr = reinterpret_cast<const float4*>(W3 + o * 128);
        const float4* hr = reinterpret_cast<const float4*>(h2[kl]);
        float acc = b3[o];
        #pragma unroll
        for (int i = 0; i < 32; ++i) {
            float4 w = wr[i]; float4 a = hr[i];
            acc = fmaf(w.x, a.x, acc); acc = fmaf(w.y, a.y, acc);
            acc = fmaf(w.z, a.z, acc); acc = fmaf(w.w, a.w, acc);
        }
        h3[kl][o] = elu_f(acc);
    }
    __syncthreads();

    // ---- layer 4: this block's 196 outputs, dot over 256, 2 k each ----
    if (t < 196) {
        const int j = jq * 196 + t;
        const float4* wr = reinterpret_cast<const float4*>(W4 + j * 256);
        const float4* h0 = reinterpret_cast<const float4*>(h3[0]);
        const float4* hA = reinterpret_cast<const float4*>(h3[1]);
        float bb = b4[j];
        float a0 = bb, a1 = bb;
        #pragma unroll 8
        for (int i = 0; i < 64; ++i) {
            float4 w = wr[i];
            float4 x0 = h0[i], x1 = hA[i];
            a0 = fmaf(w.x, x0.x, a0); a0 = fmaf(w.y, x0.y, a0);
            a0 = fmaf(w.z, x0.z, a0); a0 = fmaf(w.w, x0.w, a0);
            a1 = fmaf(w.x, x1.x, a1); a1 = fmaf(w.y, x1.y, a1);
            a1 = fmaf(w.z, x1.z, a1); a1 = fmaf(w.w, x1.w, a1);
        }
        float2 r = make_float2(sigmoid_f(a0), sigmoid_f(a1));
        *reinterpret_cast<float2*>(PT + j * 256 + k0) = r;
    }
}

// ---------------------------------------------------------------------------
// K2: quad + ll + per-(row, k-quarter) softmax partials + fused finalize.
// grid = 512 blocks = 4 k-quarters (HIGH bits, so CU-neighbors share the
// P-quarter in cache) x 128 n-tiles (4 rows staged in LDS).
// Wave w owns d-chunk [w*196,(w+1)*196). Lane: kv = l&15 (float4 in the
// quarter), dsub = l>>4 (49-d sub-chunk). Each lane loads one P^T float4
// and amortizes it over 4 X-rows in registers (load:VALU = 1 KB : 32 ops).
// part[row][q] = {m, sum e^(ll-m), sum e^(ll-m)*ll} written as AGENT-scope
// atomic stores (per-XCD L2 is not cross-coherent; 12-B-strided entries
// false-share cache lines across blocks -> plain stores are unsafe).
// The 512th block to finish (device atomicAdd + threadfence acquire) merges
// all partials (exact log-sum-exp merge) and writes the mean to out[0].
// ---------------------------------------------------------------------------
__global__ __launch_bounds__(256) void quad_part_kernel(
    const float* __restrict__ X, const float* __restrict__ log_std,
    const float* __restrict__ PT, float* __restrict__ part,
    unsigned int* __restrict__ counter, float* __restrict__ out)
{
    __shared__ __align__(16) float Xs[4][784];
    __shared__ float red[4][16][17];   // [wave][kv][r*4+j], padded
    __shared__ int is_last;
    __shared__ float red2[4];

    const int t  = threadIdx.x;
    const int nb = blockIdx.x & 127;  // n-tile 0..127
    const int bq = blockIdx.x >> 7;   // k-quarter 0..3
    const int n0 = nb * 4;

    {
        const float4* X4  = reinterpret_cast<const float4*>(X + n0 * 784);
        float4*       Xs4 = reinterpret_cast<float4*>(&Xs[0][0]);
        for (int i = t; i < 784; i += 256) Xs4[i] = X4[i];
    }
    __syncthreads();

    const int w    = t >> 6, l = t & 63;
    const int kv   = l & 15;
    const int dsub = l >> 4;
    const int db   = w * 196 + dsub * 49;

    const float4* P4 = reinterpret_cast<const float4*>(PT) + bq * 16 + kv;

    float a00=0.f,a01=0.f,a02=0.f,a03=0.f;
    float a10=0.f,a11=0.f,a12=0.f,a13=0.f;
    float a20=0.f,a21=0.f,a22=0.f,a23=0.f;
    float a30=0.f,a31=0.f,a32=0.f,a33=0.f;

    #pragma unroll 7
    for (int i = 0; i < 49; ++i) {
        const int d = db + i;
        float4 p = P4[d * 64];
        float x0 = Xs[0][d], x1 = Xs[1][d], x2 = Xs[2][d], x3 = Xs[3][d];
        float e;
        e = x0-p.x; a00=fmaf(e,e,a00);  e = x0-p.y; a01=fmaf(e,e,a01);
        e = x0-p.z; a02=fmaf(e,e,a02);  e = x0-p.w; a03=fmaf(e,e,a03);
        e = x1-p.x; a10=fmaf(e,e,a10);  e = x1-p.y; a11=fmaf(e,e,a11);
        e = x1-p.z; a12=fmaf(e,e,a12);  e = x1-p.w; a13=fmaf(e,e,a13);
        e = x2-p.x; a20=fmaf(e,e,a20);  e = x2-p.y; a21=fmaf(e,e,a21);
        e = x2-p.z; a22=fmaf(e,e,a22);  e = x2-p.w; a23=fmaf(e,e,a23);
        e = x3-p.x; a30=fmaf(e,e,a30);  e = x3-p.y; a31=fmaf(e,e,a31);
        e = x3-p.z; a32=fmaf(e,e,a32);  e = x3-p.w; a33=fmaf(e,e,a33);
    }

    // reduce across the 4 dsub groups (lanes l, l^16, l^32, l^48)
    #define RED2(v) v += __shfl_xor(v, 16); v += __shfl_xor(v, 32);
    RED2(a00) RED2(a01) RED2(a02) RED2(a03)
    RED2(a10) RED2(a11) RED2(a12) RED2(a13)
    RED2(a20) RED2(a21) RED2(a22) RED2(a23)
    RED2(a30) RED2(a31) RED2(a32) RED2(a33)
    #undef RED2

    // cross-wave (d-chunk) reduce via LDS transpose
    if (l < 16) {
        float* rr = red[w][l];
        rr[0]=a00;  rr[1]=a01;  rr[2]=a02;  rr[3]=a03;
        rr[4]=a10;  rr[5]=a11;  rr[6]=a12;  rr[7]=a13;
        rr[8]=a20;  rr[9]=a21;  rr[10]=a22; rr[11]=a23;
        rr[12]=a30; rr[13]=a31; rr[14]=a32; rr[15]=a33;
    }
    __syncthreads();

    // wave w finalizes row r = w; lanes 0..15 hold the 64 k of this quarter
    if (l < 16) {
        const int r4 = w * 4;
        float q0 = red[0][l][r4+0] + red[1][l][r4+0] + red[2][l][r4+0] + red[3][l][r4+0];
        float q1 = red[0][l][r4+1] + red[1][l][r4+1] + red[2][l][r4+1] + red[3][l][r4+1];
        float q2 = red[0][l][r4+2] + red[1][l][r4+2] + red[2][l][r4+2] + red[3][l][r4+2];
        float q3 = red[0][l][r4+3] + red[1][l][r4+3] + red[2][l][r4+3] + red[3][l][r4+3];

        float ls  = log_std[0];
        float s   = expf(ls);
        float inv = 1.0f / (s + 0.001f);
        float log_norm = -0.5f * 784.0f * LOG_2PI - 0.5f * 784.0f * ls;

        float ll0 = log_norm - 0.5f * q0 * inv;
        float ll1 = log_norm - 0.5f * q1 * inv;
        float ll2 = log_norm - 0.5f * q2 * inv;
        float ll3 = log_norm - 0.5f * q3 * inv;

        float m = fmaxf(fmaxf(ll0, ll1), fmaxf(ll2, ll3));
        #pragma unroll
        for (int off = 1; off < 16; off <<= 1)
            m = fmaxf(m, __shfl_xor(m, off));

        float e0 = expf(ll0 - m), e1 = expf(ll1 - m);
        float e2 = expf(ll2 - m), e3 = expf(ll3 - m);
        float s0 = (e0 + e1) + (e2 + e3);
        float s1 = fmaf(e0, ll0, fmaf(e1, ll1, fmaf(e2, ll2, e3 * ll3)));
        #pragma unroll
        for (int off = 1; off < 16; off <<= 1) {
            s0 += __shfl_xor(s0, off);
            s1 += __shfl_xor(s1, off);
        }

        if (l == 0) {
            float* pp = part + ((n0 + w) * 4 + bq) * 3;
            __hip_atomic_store(&pp[0], m,  __ATOMIC_RELAXED, __HIP_MEMORY_SCOPE_AGENT);
            __hip_atomic_store(&pp[1], s0, __ATOMIC_RELAXED, __HIP_MEMORY_SCOPE_AGENT);
            __hip_atomic_store(&pp[2], s1, __ATOMIC_RELAXED, __HIP_MEMORY_SCOPE_AGENT);
        }
    }
    __syncthreads();

    // ---- last-block finalize (exact log-sum-exp merge of 4 quarters/row) ----
    if (t == 0) {
        __threadfence();   // agent release: part stores ordered before counter
        unsigned int old = atomicAdd(counter, 1u);
        is_last = (old == 511u);
    }
    __syncthreads();
    if (!is_last) return;

    __threadfence();       // agent acquire: see all blocks' part stores
    float v = 0.0f;
    #pragma unroll
    for (int h = 0; h < 2; ++h) {
        const float* pp = part + (t + h * 256) * 12;
        float m0 = __hip_atomic_load(&pp[0],  __ATOMIC_RELAXED, __HIP_MEMORY_SCOPE_AGENT);
        float s00 = __hip_atomic_load(&pp[1], __ATOMIC_RELAXED, __HIP_MEMORY_SCOPE_AGENT);
        float s10 = __hip_atomic_load(&pp[2], __ATOMIC_RELAXED, __HIP_MEMORY_SCOPE_AGENT);
        float m1 = __hip_atomic_load(&pp[3],  __ATOMIC_RELAXED, __HIP_MEMORY_SCOPE_AGENT);
        float s01 = __hip_atomic_load(&pp[4], __ATOMIC_RELAXED, __HIP_MEMORY_SCOPE_AGENT);
        float s11 = __hip_atomic_load(&pp[5], __ATOMIC_RELAXED, __HIP_MEMORY_SCOPE_AGENT);
        float m2 = __hip_atomic_load(&pp[6],  __ATOMIC_RELAXED, __HIP_MEMORY_SCOPE_AGENT);
        float s02 = __hip_atomic_load(&pp[7], __ATOMIC_RELAXED, __HIP_MEMORY_SCOPE_AGENT);
        float s12 = __hip_atomic_load(&pp[8], __ATOMIC_RELAXED, __HIP_MEMORY_SCOPE_AGENT);
        float m3 = __hip_atomic_load(&pp[9],  __ATOMIC_RELAXED, __HIP_MEMORY_SCOPE_AGENT);
        float s03 = __hip_atomic_load(&pp[10],__ATOMIC_RELAXED, __HIP_MEMORY_SCOPE_AGENT);
        float s13 = __hip_atomic_load(&pp[11],__ATOMIC_RELAXED, __HIP_MEMORY_SCOPE_AGENT);

        float M = fmaxf(fmaxf(m0, m1), fmaxf(m2, m3));
        float f0 = expf(m0 - M), f1 = expf(m1 - M);
        float f2 = expf(m2 - M), f3 = expf(m3 - M);
        float S0 = fmaf(s00, f0, fmaf(s01, f1, fmaf(s02, f2, s03 * f3)));
        float S1 = fmaf(s10, f0, fmaf(s11, f1, fmaf(s12, f2, s13 * f3)));
        v += S1 / S0;
    }
    for (int off = 32; off > 0; off >>= 1)
        v += __shfl_down(v, off);
    if ((t & 63) == 0) red2[t >> 6] = v;
    __syncthreads();
    if (t == 0)
        out[0] = (red2[0] + red2[1] + red2[2] + red2[3]) * (1.0f / 512.0f);
}

extern "C" void kernel_launch(void* const* d_in, const int* in_sizes, int n_in,
                              void* d_out, int out_size, void* d_ws, size_t ws_size,
                              hipStream_t stream) {
    // setup_inputs() order: X, z, log_std, W1, b1, W2, b2, W3, b3, W4, b4
    const float* X       = (const float*)d_in[0];
    const float* z       = (const float*)d_in[1];
    const float* log_std = (const float*)d_in[2];
    const float* W1      = (const float*)d_in[3];
    const float* b1      = (const float*)d_in[4];
    const float* W2      = (const float*)d_in[5];
    const float* b2      = (const float*)d_in[6];
    const float* W3      = (const float*)d_in[7];
    const float* b3      = (const float*)d_in[8];
    const float* W4      = (const float*)d_in[9];
    const float* b4      = (const float*)d_in[10];
    float* out = (float*)d_out;

    float*        wsf     = (float*)d_ws;
    float*        PT      = wsf;            // 784 x 256 floats (P transposed)
    float*        part    = wsf + 200704;   // 512 rows x 4 quarters x {m,s0,s1}
    unsigned int* counter = (unsigned int*)(wsf + 206848);

    decoder_kernel<<<512, 256, 0, stream>>>(z, W1, b1, W2, b2, W3, b3, W4, b4,
                                            PT, counter);
    quad_part_kernel<<<512, 256, 0, stream>>>(X, log_std, PT, part, counter, out);
}

// Round 11
// 115.301 us; speedup vs baseline: 1.1082x; 1.1082x over previous
//
#include <hip/hip_runtime.h>
#include <math.h>

// ln(2*pi) in f32 (reference uses jnp.log(2*PI) with truncated f32 PI)
#define LOG_2PI 1.8378770664093453f

__device__ __forceinline__ float elu_f(float x) {
    return x > 0.0f ? x : expm1f(x);
}
__device__ __forceinline__ float sigmoid_f(float x) {
    return 1.0f / (1.0f + expf(-x));
}

// ---------------------------------------------------------------------------
// K1: decoder. grid = 256 blocks = 64 k-tiles (4 latent rows) x 4 j-quarters.
// Layers 1-3 computed redundantly per j-quarter (cheap); layer 4 does 196
// outputs per block, one per thread. Stores P^T (784 x 256) so K2's loads
// are lane-coalesced.
// ---------------------------------------------------------------------------
__global__ __launch_bounds__(256) void decoder_kernel(
    const float* __restrict__ z,
    const float* __restrict__ W1, const float* __restrict__ b1,
    const float* __restrict__ W2, const float* __restrict__ b2,
    const float* __restrict__ W3, const float* __restrict__ b3,
    const float* __restrict__ W4, const float* __restrict__ b4,
    float* __restrict__ PT)
{
    __shared__ __align__(16) float h1[4][64];
    __shared__ __align__(16) float h2[4][128];
    __shared__ __align__(16) float h3[4][256];

    const int t  = threadIdx.x;
    const int kt = blockIdx.x >> 2;   // 0..63
    const int jq = blockIdx.x & 3;    // 0..3
    const int k0 = kt * 4;

    // ---- layer 1: (4 k) x 64 outputs, dot over 2 ----
    {
        int kl = t >> 6, o = t & 63;
        float z0 = z[(k0 + kl) * 2 + 0];
        float z1 = z[(k0 + kl) * 2 + 1];
        float v = fmaf(z0, W1[o * 2 + 0], fmaf(z1, W1[o * 2 + 1], b1[o]));
        h1[kl][o] = elu_f(v);
    }
    __syncthreads();

    // ---- layer 2: (4 k) x 128 outputs, dot over 64 ----
    for (int idx = t; idx < 512; idx += 256) {
        int kl = idx >> 7, o = idx & 127;
        const float4* wr = reinterpret_cast<const float4*>(W2 + o * 64);
        const float4* hr = reinterpret_cast<const float4*>(h1[kl]);
        float acc = b2[o];
        #pragma unroll
        for (int i = 0; i < 16; ++i) {
            float4 w = wr[i]; float4 a = hr[i];
            acc = fmaf(w.x, a.x, acc); acc = fmaf(w.y, a.y, acc);
            acc = fmaf(w.z, a.z, acc); acc = fmaf(w.w, a.w, acc);
        }
        h2[kl][o] = elu_f(acc);
    }
    __syncthreads();

    // ---- layer 3: (4 k) x 256 outputs, dot over 128 ----
    for (int idx = t; idx < 1024; idx += 256) {
        int kl = idx >> 8, o = idx & 255;
        const float4* wr = reinterpret_cast<const float4*>(W3 + o * 128);
        const float4* hr = reinterpret_cast<const float4*>(h2[kl]);
        float acc = b3[o];
        #pragma unroll
        for (int i = 0; i < 32; ++i) {
            float4 w = wr[i]; float4 a = hr[i];
            acc = fmaf(w.x, a.x, acc); acc = fmaf(w.y, a.y, acc);
            acc = fmaf(w.z, a.z, acc); acc = fmaf(w.w, a.w, acc);
        }
        h3[kl][o] = elu_f(acc);
    }
    __syncthreads();

    // ---- layer 4: this block's 196 outputs, dot over 256, 4 k each ----
    if (t < 196) {
        const int j = jq * 196 + t;
        const float4* wr = reinterpret_cast<const float4*>(W4 + j * 256);
        const float4* h0 = reinterpret_cast<const float4*>(h3[0]);
        const float4* hA = reinterpret_cast<const float4*>(h3[1]);
        const float4* hB = reinterpret_cast<const float4*>(h3[2]);
        const float4* hC = reinterpret_cast<const float4*>(h3[3]);
        float bb = b4[j];
        float a0 = bb, a1 = bb, a2 = bb, a3 = bb;
        #pragma unroll 8
        for (int i = 0; i < 64; ++i) {
            float4 w = wr[i];
            float4 x0 = h0[i], x1 = hA[i], x2 = hB[i], x3 = hC[i];
            a0 = fmaf(w.x, x0.x, a0); a0 = fmaf(w.y, x0.y, a0);
            a0 = fmaf(w.z, x0.z, a0); a0 = fmaf(w.w, x0.w, a0);
            a1 = fmaf(w.x, x1.x, a1); a1 = fmaf(w.y, x1.y, a1);
            a1 = fmaf(w.z, x1.z, a1); a1 = fmaf(w.w, x1.w, a1);
            a2 = fmaf(w.x, x2.x, a2); a2 = fmaf(w.y, x2.y, a2);
            a2 = fmaf(w.z, x2.z, a2); a2 = fmaf(w.w, x2.w, a2);
            a3 = fmaf(w.x, x3.x, a3); a3 = fmaf(w.y, x3.y, a3);
            a3 = fmaf(w.z, x3.z, a3); a3 = fmaf(w.w, x3.w, a3);
        }
        float4 r = make_float4(sigmoid_f(a0), sigmoid_f(a1),
                               sigmoid_f(a2), sigmoid_f(a3));
        *reinterpret_cast<float4*>(PT + j * 256 + k0) = r;
    }
}

// ---------------------------------------------------------------------------
// K2: quad + ll + per-(row, k-quarter) softmax partials.
// grid = 512 blocks = 4 k-quarters (HIGH bits, so CU-neighbors share the
// P-quarter in cache) x 128 n-tiles (4 rows staged in LDS).
// Wave w owns d-chunk [w*196,(w+1)*196). Lane: kv = l&15 (float4 in the
// quarter), dsub = l>>4 (49-d sub-chunk). Each lane loads one P^T float4
// and amortizes it over 4 X-rows in registers: load:VALU = 1 KB : 32 ops,
// at 8 waves/CU (2/SIMD). acc indices all compile-time (no scratch).
// d-reduce: shfl_xor(16,32) across dsub, padded-LDS transpose across waves;
// then 16-lane softmax partial per (row, quarter).
// Writes part[row][q] = {m, sum e^(ll-m), sum e^(ll-m)*ll}.
// ---------------------------------------------------------------------------
__global__ __launch_bounds__(256) void quad_part_kernel(
    const float* __restrict__ X, const float* __restrict__ log_std,
    const float* __restrict__ PT, float* __restrict__ part)
{
    __shared__ __align__(16) float Xs[4][784];
    __shared__ float red[4][16][17];   // [wave][kv][r*4+j], padded

    const int t  = threadIdx.x;
    const int nb = blockIdx.x & 127;  // n-tile 0..127
    const int bq = blockIdx.x >> 7;   // k-quarter 0..3
    const int n0 = nb * 4;

    {
        const float4* X4  = reinterpret_cast<const float4*>(X + n0 * 784);
        float4*       Xs4 = reinterpret_cast<float4*>(&Xs[0][0]);
        for (int i = t; i < 784; i += 256) Xs4[i] = X4[i];
    }
    __syncthreads();

    const int w    = t >> 6, l = t & 63;
    const int kv   = l & 15;
    const int dsub = l >> 4;
    const int db   = w * 196 + dsub * 49;

    const float4* P4 = reinterpret_cast<const float4*>(PT) + bq * 16 + kv;

    float a00=0.f,a01=0.f,a02=0.f,a03=0.f;
    float a10=0.f,a11=0.f,a12=0.f,a13=0.f;
    float a20=0.f,a21=0.f,a22=0.f,a23=0.f;
    float a30=0.f,a31=0.f,a32=0.f,a33=0.f;

    #pragma unroll 7
    for (int i = 0; i < 49; ++i) {
        const int d = db + i;
        float4 p = P4[d * 64];
        float x0 = Xs[0][d], x1 = Xs[1][d], x2 = Xs[2][d], x3 = Xs[3][d];
        float e;
        e = x0-p.x; a00=fmaf(e,e,a00);  e = x0-p.y; a01=fmaf(e,e,a01);
        e = x0-p.z; a02=fmaf(e,e,a02);  e = x0-p.w; a03=fmaf(e,e,a03);
        e = x1-p.x; a10=fmaf(e,e,a10);  e = x1-p.y; a11=fmaf(e,e,a11);
        e = x1-p.z; a12=fmaf(e,e,a12);  e = x1-p.w; a13=fmaf(e,e,a13);
        e = x2-p.x; a20=fmaf(e,e,a20);  e = x2-p.y; a21=fmaf(e,e,a21);
        e = x2-p.z; a22=fmaf(e,e,a22);  e = x2-p.w; a23=fmaf(e,e,a23);
        e = x3-p.x; a30=fmaf(e,e,a30);  e = x3-p.y; a31=fmaf(e,e,a31);
        e = x3-p.z; a32=fmaf(e,e,a32);  e = x3-p.w; a33=fmaf(e,e,a33);
    }

    // reduce across the 4 dsub groups (lanes l, l^16, l^32, l^48)
    #define RED2(v) v += __shfl_xor(v, 16); v += __shfl_xor(v, 32);
    RED2(a00) RED2(a01) RED2(a02) RED2(a03)
    RED2(a10) RED2(a11) RED2(a12) RED2(a13)
    RED2(a20) RED2(a21) RED2(a22) RED2(a23)
    RED2(a30) RED2(a31) RED2(a32) RED2(a33)
    #undef RED2

    // cross-wave (d-chunk) reduce via LDS transpose
    if (l < 16) {
        float* rr = red[w][l];
        rr[0]=a00;  rr[1]=a01;  rr[2]=a02;  rr[3]=a03;
        rr[4]=a10;  rr[5]=a11;  rr[6]=a12;  rr[7]=a13;
        rr[8]=a20;  rr[9]=a21;  rr[10]=a22; rr[11]=a23;
        rr[12]=a30; rr[13]=a31; rr[14]=a32; rr[15]=a33;
    }
    __syncthreads();

    // wave w finalizes row r = w; lanes 0..15 hold the 64 k of this quarter
    if (l < 16) {
        const int r4 = w * 4;
        float q0 = red[0][l][r4+0] + red[1][l][r4+0] + red[2][l][r4+0] + red[3][l][r4+0];
        float q1 = red[0][l][r4+1] + red[1][l][r4+1] + red[2][l][r4+1] + red[3][l][r4+1];
        float q2 = red[0][l][r4+2] + red[1][l][r4+2] + red[2][l][r4+2] + red[3][l][r4+2];
        float q3 = red[0][l][r4+3] + red[1][l][r4+3] + red[2][l][r4+3] + red[3][l][r4+3];

        float ls  = log_std[0];
        float s   = expf(ls);
        float inv = 1.0f / (s + 0.001f);
        float log_norm = -0.5f * 784.0f * LOG_2PI - 0.5f * 784.0f * ls;

        float ll0 = log_norm - 0.5f * q0 * inv;
        float ll1 = log_norm - 0.5f * q1 * inv;
        float ll2 = log_norm - 0.5f * q2 * inv;
        float ll3 = log_norm - 0.5f * q3 * inv;

        float m = fmaxf(fmaxf(ll0, ll1), fmaxf(ll2, ll3));
        #pragma unroll
        for (int off = 1; off < 16; off <<= 1)
            m = fmaxf(m, __shfl_xor(m, off));

        float e0 = expf(ll0 - m), e1 = expf(ll1 - m);
        float e2 = expf(ll2 - m), e3 = expf(ll3 - m);
        float s0 = (e0 + e1) + (e2 + e3);
        float s1 = fmaf(e0, ll0, fmaf(e1, ll1, fmaf(e2, ll2, e3 * ll3)));
        #pragma unroll
        for (int off = 1; off < 16; off <<= 1) {
            s0 += __shfl_xor(s0, off);
            s1 += __shfl_xor(s1, off);
        }

        if (l == 0) {
            float* pp = part + ((n0 + w) * 4 + bq) * 3;
            pp[0] = m; pp[1] = s0; pp[2] = s1;
        }
    }
}

// ---------------------------------------------------------------------------
// K3: merge the 4 k-quarter partials per row (exact log-sum-exp merge),
// mean over the 512 rows -> d_out[0]. One block.
// ---------------------------------------------------------------------------
__global__ __launch_bounds__(256) void finalize_kernel(
    const float* __restrict__ part, float* __restrict__ out)
{
    __shared__ float red[4];
    const int t = threadIdx.x;
    float v = 0.0f;
    #pragma unroll
    for (int h = 0; h < 2; ++h) {
        const float* pp = part + (t + h * 256) * 12;
        float M = fmaxf(fmaxf(pp[0], pp[3]), fmaxf(pp[6], pp[9]));
        float S0 = 0.0f, S1 = 0.0f;
        #pragma unroll
        for (int q = 0; q < 4; ++q) {
            float f = expf(pp[q * 3] - M);
            S0 = fmaf(pp[q * 3 + 1], f, S0);
            S1 = fmaf(pp[q * 3 + 2], f, S1);
        }
        v += S1 / S0;
    }
    for (int off = 32; off > 0; off >>= 1)
        v += __shfl_down(v, off);
    if ((t & 63) == 0) red[t >> 6] = v;
    __syncthreads();
    if (t == 0)
        out[0] = (red[0] + red[1] + red[2] + red[3]) * (1.0f / 512.0f);
}

extern "C" void kernel_launch(void* const* d_in, const int* in_sizes, int n_in,
                              void* d_out, int out_size, void* d_ws, size_t ws_size,
                              hipStream_t stream) {
    // setup_inputs() order: X, z, log_std, W1, b1, W2, b2, W3, b3, W4, b4
    const float* X       = (const float*)d_in[0];
    const float* z       = (const float*)d_in[1];
    const float* log_std = (const float*)d_in[2];
    const float* W1      = (const float*)d_in[3];
    const float* b1      = (const float*)d_in[4];
    const float* W2      = (const float*)d_in[5];
    const float* b2      = (const float*)d_in[6];
    const float* W3      = (const float*)d_in[7];
    const float* b3      = (const float*)d_in[8];
    const float* W4      = (const float*)d_in[9];
    const float* b4      = (const float*)d_in[10];
    float* out = (float*)d_out;

    float* wsf  = (float*)d_ws;
    float* PT   = wsf;            // 784 x 256 floats (P transposed)
    float* part = wsf + 200704;   // 512 rows x 4 quarters x {m, s0, s1}

    decoder_kernel<<<256, 256, 0, stream>>>(z, W1, b1, W2, b2, W3, b3, W4, b4, PT);
    quad_part_kernel<<<512, 256, 0, stream>>>(X, log_std, PT, part);
    finalize_kernel<<<1, 256, 0, stream>>>(part, out);
}